// Round 11
// baseline (949.765 us; speedup 1.0000x reference)
//
#include <hip/hip_runtime.h>
#include <math.h>

#define TT 64
#define BB 64
#define DD 512
#define HH 512
#define G4 2048
#define OO 128

typedef unsigned short us16;
typedef __attribute__((ext_vector_type(8))) short bf16x8;
typedef __attribute__((ext_vector_type(4))) float f32x4;
typedef __attribute__((ext_vector_type(4))) unsigned u32x4;

__device__ __forceinline__ unsigned pk_bf16(float lo, float hi) {
  unsigned r;
  asm volatile("v_cvt_pk_bf16_f32 %0, %1, %2" : "=v"(r) : "v"(lo), "v"(hi));
  return r;
}

// fast gate math (bf16 tolerance is ample)
__device__ __forceinline__ float fsigm(float v) { return 1.f / (1.f + __expf(-v)); }
__device__ __forceinline__ float ftanh(float v) { return 1.f - 2.f / (__expf(2.f * v) + 1.f); }

// coherent (LLC-direct) accesses for cross-block data
__device__ __forceinline__ u32x4 load_b128_cc(const void* p) {
  u32x4 r;
  asm volatile("global_load_dwordx4 %0, %1, off sc0 sc1" : "=v"(r) : "v"(p));
  return r;
}
__device__ __forceinline__ void store_b128_cc(void* p, u32x4 v) {
  asm volatile("global_store_dwordx4 %0, %1, off sc0 sc1" ::"v"(p), "v"(v) : "memory");
}

// ============================================================================
// Phase A: G[t,b,j] = x_t @ Wih_t^T + b_ih + b_hh   via bf16 MFMA  (unchanged)
// ============================================================================
__global__ __launch_bounds__(256) void phaseA_mfma(
    const float* __restrict__ x, const float* __restrict__ wih,
    const float* __restrict__ bih, const float* __restrict__ bhh,
    float* __restrict__ Gb) {
  __shared__ us16 xa[2][64][64];
  __shared__ us16 wbuf[2][128][64];
  const int tid = threadIdx.x;
  const int t = blockIdx.y;
  const int j0 = blockIdx.x * 128;
  const int wv = tid >> 6, lane = tid & 63;
  const int wm = wv & 1, wn = wv >> 1;
  const float* xb = x + (size_t)t * (BB * DD);
  const float* wg = wih + (size_t)t * (G4 * DD) + (size_t)j0 * DD;

  float4 xr[2][2], wr[4][2];
  int xrow[2], xc[2], wrow[4], wc[4];
#pragma unroll
  for (int i = 0; i < 2; i++) { int cid = tid + i * 256; xrow[i] = cid >> 3; xc[i] = cid & 7; }
#pragma unroll
  for (int i = 0; i < 4; i++) { int cid = tid + i * 256; wrow[i] = cid >> 3; wc[i] = cid & 7; }

  auto loadx = [&](int k0) {
#pragma unroll
    for (int i = 0; i < 2; i++) {
      const float* p = xb + xrow[i] * DD + k0 + xc[i] * 8;
      xr[i][0] = *(const float4*)p; xr[i][1] = *(const float4*)(p + 4);
    }
  };
  auto loadw = [&](int k0) {
#pragma unroll
    for (int i = 0; i < 4; i++) {
      const float* p = wg + (size_t)wrow[i] * DD + k0 + wc[i] * 8;
      wr[i][0] = *(const float4*)p; wr[i][1] = *(const float4*)(p + 4);
    }
  };
  auto store = [&](int buf) {
#pragma unroll
    for (int i = 0; i < 2; i++) {
      uint4 u;
      u.x = pk_bf16(xr[i][0].x, xr[i][0].y); u.y = pk_bf16(xr[i][0].z, xr[i][0].w);
      u.z = pk_bf16(xr[i][1].x, xr[i][1].y); u.w = pk_bf16(xr[i][1].z, xr[i][1].w);
      int p = xc[i] ^ (xrow[i] & 7);
      *(uint4*)&xa[buf][xrow[i]][p * 8] = u;
    }
#pragma unroll
    for (int i = 0; i < 4; i++) {
      uint4 u;
      u.x = pk_bf16(wr[i][0].x, wr[i][0].y); u.y = pk_bf16(wr[i][0].z, wr[i][0].w);
      u.z = pk_bf16(wr[i][1].x, wr[i][1].y); u.w = pk_bf16(wr[i][1].z, wr[i][1].w);
      int p = wc[i] ^ (wrow[i] & 7);
      *(uint4*)&wbuf[buf][wrow[i]][p * 8] = u;
    }
  };

  loadx(0); loadw(0); store(0);
  __syncthreads();

  f32x4 zero = {0.f, 0.f, 0.f, 0.f};
  f32x4 acc[2][4];
#pragma unroll
  for (int mt = 0; mt < 2; mt++)
#pragma unroll
    for (int nt = 0; nt < 4; nt++) acc[mt][nt] = zero;

  for (int s = 0; s < 8; s++) {
    const int nb = s & 1;
    if (s < 7) { loadx((s + 1) * 64); loadw((s + 1) * 64); }
#pragma unroll
    for (int ks = 0; ks < 2; ks++) {
      const int cc = ks * 4 + (lane >> 4);
      bf16x8 a[2], b[4];
#pragma unroll
      for (int mt = 0; mt < 2; mt++) {
        int r = wm * 32 + mt * 16 + (lane & 15);
        a[mt] = *(const bf16x8*)&xa[nb][r][(cc ^ (r & 7)) * 8];
      }
#pragma unroll
      for (int nt = 0; nt < 4; nt++) {
        int r = wn * 64 + nt * 16 + (lane & 15);
        b[nt] = *(const bf16x8*)&wbuf[nb][r][(cc ^ (r & 7)) * 8];
      }
#pragma unroll
      for (int mt = 0; mt < 2; mt++)
#pragma unroll
        for (int nt = 0; nt < 4; nt++)
          acc[mt][nt] = __builtin_amdgcn_mfma_f32_16x16x32_bf16(a[mt], b[nt], acc[mt][nt], 0, 0, 0);
    }
    __syncthreads();
    if (s < 7) store(nb ^ 1);
    __syncthreads();
  }

  float bias[4]; int jn[4];
#pragma unroll
  for (int nt = 0; nt < 4; nt++) {
    jn[nt] = j0 + wn * 64 + nt * 16 + (lane & 15);
    bias[nt] = bih[t * G4 + jn[nt]] + bhh[t * G4 + jn[nt]];
  }
#pragma unroll
  for (int mt = 0; mt < 2; mt++)
#pragma unroll
    for (int nt = 0; nt < 4; nt++)
#pragma unroll
      for (int e = 0; e < 4; e++) {
        int brow = wm * 32 + mt * 16 + (lane >> 4) * 4 + e;
        Gb[((size_t)t * BB + brow) * G4 + jn[nt]] = acc[mt][nt][e] + bias[nt];
      }
}

// ============================================================================
// Persistent LSTM stepper — round-10 protocol + dedicated W-streamer wave.
// 256 blocks (bh = bid&1, ug = bid>>1 -> units ug*4..+3), 5 waves (320 thr):
//   waves 0-3: GEMM (wm = wv&1 batch-16-half, kq = wv>>1 k-256-half) + wave0
//     epilogue/publish — EXACT round-10 structure, but W comes from LDS
//     (ds_read) instead of own-vmcnt fp32 prefetch: their vmcnt holds ONLY
//     poll loads -> no W-drain on the critical path.
//   wave 4: Whh streamer. Two register sets, issues W(t+2) before consuming
//     W(t+1) -> each W slab gets a FULL step of HBM time on its own vmcnt.
// h in global as 16B TAGGED RECORDS [8B = 4 bf16][4B tag][pad], 2-slot
// ping-pong, sc0/sc1. Publish = data store; poll = data-carrying. t=0 skips
// MFMA entirely (h=0; also avoids NaN from uninitialized W LDS).
// ============================================================================
__global__ __launch_bounds__(320, 1) void lstm_persist(
    const float* __restrict__ whh, const float* __restrict__ Gb,
    const int* __restrict__ lengths, char* __restrict__ hb,
    float* __restrict__ hf) {
  __shared__ us16 wbuf[2][16][512];  // 32 KB bf16 W double buffer (chunk-swizzled)
  __shared__ float gm[2][16][36];

  const int tid = threadIdx.x, bid = blockIdx.x;
  const int bh = bid & 1, ug = bid >> 1;
  const int wv = tid >> 6, lane = tid & 63;
  const int l15 = lane & 15, klg = lane >> 4;

  if (wv < 4) {
    // ================= GEMM + epilogue waves (round-10 protocol) =============
    const int wm = wv & 1, kq = wv >> 1;

    float2 gpre[4];  // Gb prefetch (wave0: 2 units per lane)
    auto prefG = [&](int tt) {
      if (wv == 0) {
        const float* gbp =
            Gb + ((size_t)tt * BB + bh * 32 + (lane & 31)) * G4 + ug * 4 + ((lane >> 5) << 1);
#pragma unroll
        for (int q = 0; q < 4; q++) gpre[q] = *(const float2*)(gbp + q * 512);
      }
    };

    const size_t cbase =
        (size_t)bh * 65536 + ((size_t)(kq * 64 + klg * 2) * 32 + wm * 16 + l15) * 16;
    const size_t pbase = (size_t)bh * 65536 + ((size_t)ug * 32 + (lane & 31)) * 16;

    const int mylen = (wv == 0) ? lengths[bh * 32 + (lane & 31)] : -2;
    float cst[2] = {0.f, 0.f};

    prefG(0);

    for (int t = 0; t < TT; t++) {
      f32x4 acc = {0.f, 0.f, 0.f, 0.f};
      if (t > 0) {
        // ---- poll records(t): data-carrying, 1 LLC RT on success ----
        u32x4 r0[8], r1[8];
        const char* sbase = hb + (size_t)(t & 1) * 131072 + cbase;
        const unsigned tg = (unsigned)t;
        bool ok;
        do {
#pragma unroll
          for (int s = 0; s < 8; s++) {
            r0[s] = load_b128_cc(sbase + (size_t)s * 4096);
            r1[s] = load_b128_cc(sbase + (size_t)s * 4096 + 512);
          }
          asm volatile("s_waitcnt vmcnt(0)" ::: "memory");
          __builtin_amdgcn_sched_barrier(0);
          ok = true;
#pragma unroll
          for (int s = 0; s < 8; s++) ok = ok && (r0[s].z == tg) && (r1[s].z == tg);
          if (!__all(ok)) {
            __builtin_amdgcn_s_sleep(1);
            ok = false;
          } else {
            ok = true;
          }
        } while (!ok);

        // ---- W fragments from streamer-filled LDS ----
        bf16x8 wf[8];
#pragma unroll
        for (int s = 0; s < 8; s++) {
          int cc = kq * 32 + s * 4 + klg;
          wf[s] = *(const bf16x8*)&wbuf[t & 1][l15][(cc ^ (l15 & 7)) * 8];
        }
#pragma unroll
        for (int s = 0; s < 8; s++) {
          u32x4 fa;
          fa.x = r0[s].x; fa.y = r0[s].y; fa.z = r1[s].x; fa.w = r1[s].y;
          acc = __builtin_amdgcn_mfma_f32_16x16x32_bf16(__builtin_bit_cast(bf16x8, fa),
                                                        wf[s], acc, 0, 0, 0);
        }
      }
      *(f32x4*)&gm[kq][l15][wm * 16 + klg * 4] = acc;

      __syncthreads();

      float2 gcur[4];
      if (wv == 0) {
#pragma unroll
        for (int q = 0; q < 4; q++) gcur[q] = gpre[q];
      }
      if (t + 1 < TT) prefG(t + 1);

      if (wv == 0) {
        const int b = lane & 31, hi = lane >> 5;
        float hv[2];
#pragma unroll
        for (int uu = 0; uu < 2; uu++) {
          const int lu = hi * 2 + uu;
          float vi = (uu ? gcur[0].y : gcur[0].x) + gm[0][0 + lu][b] + gm[1][0 + lu][b];
          float vf = (uu ? gcur[1].y : gcur[1].x) + gm[0][4 + lu][b] + gm[1][4 + lu][b];
          float vg = (uu ? gcur[2].y : gcur[2].x) + gm[0][8 + lu][b] + gm[1][8 + lu][b];
          float vo = (uu ? gcur[3].y : gcur[3].x) + gm[0][12 + lu][b] + gm[1][12 + lu][b];
          float cn = fsigm(vf) * cst[uu] + fsigm(vi) * ftanh(vg);
          cst[uu] = cn;
          hv[uu] = fsigm(vo) * ftanh(cn);
        }
        // publish FIRST (cross-block critical path), hf store after
        unsigned hw = pk_bf16(hv[0], hv[1]);
        unsigned other = __shfl_xor(hw, 32);
        if (hi == 0 && t + 1 < TT) {
          u32x4 rec;
          rec.x = hw; rec.y = other; rec.z = (unsigned)(t + 1); rec.w = 0u;
          store_b128_cc(hb + (size_t)((t + 1) & 1) * 131072 + pbase, rec);
        }
        if (mylen - 1 == t) {
          float2 o2; o2.x = hv[0]; o2.y = hv[1];
          *(float2*)&hf[(size_t)(bh * 32 + b) * HH + ug * 4 + hi * 2] = o2;
        }
      }
    }
  } else {
    // ================= W-streamer wave (wv == 4) =============================
    // lane -> row jr = lane>>2 (B-frag row), col-quarter cq = lane&3.
    // chunk ci = cq + i*4 (i = 0..15), 8 bf16 per chunk; 64 chunks per row.
    const int jr = lane >> 2, cq = lane & 3;
    const size_t srow = (size_t)((jr >> 2) * 512 + ug * 4 + (jr & 3)) * HH;
    float4 pA[32], pB[32];

    auto issueTo = [&](int tt, float4 (&p)[32]) {
      const float* wt = whh + (size_t)tt * (G4 * HH) + srow;
#pragma unroll
      for (int i = 0; i < 16; i++) {
        const float* q = wt + (size_t)(cq + i * 4) * 8;
        p[2 * i] = *(const float4*)q;
        p[2 * i + 1] = *(const float4*)(q + 4);
      }
    };
    auto writeFrom = [&](int slot, float4 (&p)[32]) {
#pragma unroll
      for (int i = 0; i < 16; i++) {
        int ci = cq + i * 4;
        u32x4 w;
        w.x = pk_bf16(p[2 * i].x, p[2 * i].y);
        w.y = pk_bf16(p[2 * i].z, p[2 * i].w);
        w.z = pk_bf16(p[2 * i + 1].x, p[2 * i + 1].y);
        w.w = pk_bf16(p[2 * i + 1].z, p[2 * i + 1].w);
        *(u32x4*)&wbuf[slot][jr][(ci ^ (jr & 7)) * 8] = w;
      }
    };

    issueTo(1, pA);  // W(1) in flight across all of iteration 0
    for (int t = 0; t < TT; t++) {
      if (t & 1) {
        if (t + 2 < TT) issueTo(t + 2, pA);
        if (t + 1 < TT) writeFrom((t + 1) & 1, pB);
      } else {
        if (t + 2 < TT) issueTo(t + 2, pB);
        if (t + 1 < TT) writeFrom((t + 1) & 1, pA);
      }
      __syncthreads();
    }
  }
}

// ============================================================================
// Final: logits = hf @ w_ho^T + b_ho, then log_softmax
// ============================================================================
__global__ __launch_bounds__(128) void finalK(const float* __restrict__ hf,
                                              const float* __restrict__ who,
                                              const float* __restrict__ bho,
                                              float* __restrict__ out) {
  int b = blockIdx.x, o = threadIdx.x;
  const float* h = hf + b * HH;
  const float* w = who + o * HH;
  float s = bho[o];
#pragma unroll 4
  for (int k = 0; k < HH; k += 4) {
    float4 hv = *(const float4*)(h + k);
    float4 wv = *(const float4*)(w + k);
    s += hv.x * wv.x + hv.y * wv.y + hv.z * wv.z + hv.w * wv.w;
  }
  __shared__ float red[2];
  __shared__ float red2[2];
  float m = s;
#pragma unroll
  for (int msk = 32; msk; msk >>= 1) m = fmaxf(m, __shfl_xor(m, msk));
  int wave = o >> 6;
  if ((o & 63) == 0) red[wave] = m;
  __syncthreads();
  m = fmaxf(red[0], red[1]);
  float e = expf(s - m);
#pragma unroll
  for (int msk = 32; msk; msk >>= 1) e += __shfl_xor(e, msk);
  if ((o & 63) == 0) red2[wave] = e;
  __syncthreads();
  float sum = red2[0] + red2[1];
  out[b * OO + o] = (s - m) - logf(sum);
}

extern "C" void kernel_launch(void* const* d_in, const int* in_sizes, int n_in,
                              void* d_out, int out_size, void* d_ws, size_t ws_size,
                              hipStream_t stream) {
  const float* x = (const float*)d_in[0];
  const float* wih = (const float*)d_in[1];
  const float* whh = (const float*)d_in[2];
  const float* bih = (const float*)d_in[3];
  const float* bhh = (const float*)d_in[4];
  const float* who = (const float*)d_in[5];
  const float* bho = (const float*)d_in[6];
  const int* lengths = (const int*)d_in[7];
  float* out = (float*)d_out;

  char* ws = (char*)d_ws;
  float* Gb = (float*)ws;                        // 33,554,432 B
  char* hb = ws + 33554432;                      // 262,144 B (2 slots x 2 halves x 4096 records)
  float* hf = (float*)(ws + 33554432 + 262144);  // 131,072 B

  (void)hipMemsetAsync(hb, 0, 262144, stream);  // clear tags (graph-replay safety)

  phaseA_mfma<<<dim3(16, 64), 256, 0, stream>>>(x, wih, bih, bhh, Gb);
  lstm_persist<<<256, 320, 0, stream>>>(whh, Gb, lengths, hb, hf);
  finalK<<<BB, 128, 0, stream>>>(hf, who, bho, out);
}

// Round 12
// 387.346 us; speedup vs baseline: 2.4520x; 2.4520x over previous
//
#include <hip/hip_runtime.h>
#include <math.h>

#define TT 64
#define BB 64
#define DD 512
#define HH 512
#define G4 2048
#define OO 128

typedef unsigned short us16;
typedef __attribute__((ext_vector_type(8))) short bf16x8;
typedef __attribute__((ext_vector_type(4))) float f32x4;
typedef __attribute__((ext_vector_type(4))) unsigned u32x4;

__device__ __forceinline__ unsigned pk_bf16(float lo, float hi) {
  unsigned r;
  asm volatile("v_cvt_pk_bf16_f32 %0, %1, %2" : "=v"(r) : "v"(lo), "v"(hi));
  return r;
}

// fast gate math (bf16 tolerance is ample)
__device__ __forceinline__ float fsigm(float v) { return 1.f / (1.f + __expf(-v)); }
__device__ __forceinline__ float ftanh(float v) { return 1.f - 2.f / (__expf(2.f * v) + 1.f); }

// coherent (LLC-direct) accesses for cross-block data
__device__ __forceinline__ u32x4 load_b128_cc(const void* p) {
  u32x4 r;
  asm volatile("global_load_dwordx4 %0, %1, off sc0 sc1" : "=v"(r) : "v"(p));
  return r;
}
__device__ __forceinline__ void store_b128_cc(void* p, u32x4 v) {
  asm volatile("global_store_dwordx4 %0, %1, off sc0 sc1" ::"v"(p), "v"(v) : "memory");
}

// HBM -> LDS direct (16 B per lane, dest = uniform base + lane*16)
__device__ __forceinline__ void gload_lds16(const void* g, void* l) {
  __builtin_amdgcn_global_load_lds(
      (const __attribute__((address_space(1))) unsigned int*)g,
      (__attribute__((address_space(3))) unsigned int*)l, 16, 0, 0);
}

// ============================================================================
// Phase A: G[t,b,j] = x_t @ Wih_t^T + b_ih + b_hh   via bf16 MFMA  (unchanged)
// ============================================================================
__global__ __launch_bounds__(256) void phaseA_mfma(
    const float* __restrict__ x, const float* __restrict__ wih,
    const float* __restrict__ bih, const float* __restrict__ bhh,
    float* __restrict__ Gb) {
  __shared__ us16 xa[2][64][64];
  __shared__ us16 wbuf[2][128][64];
  const int tid = threadIdx.x;
  const int t = blockIdx.y;
  const int j0 = blockIdx.x * 128;
  const int wv = tid >> 6, lane = tid & 63;
  const int wm = wv & 1, wn = wv >> 1;
  const float* xb = x + (size_t)t * (BB * DD);
  const float* wg = wih + (size_t)t * (G4 * DD) + (size_t)j0 * DD;

  float4 xr[2][2], wr[4][2];
  int xrow[2], xc[2], wrow[4], wc[4];
#pragma unroll
  for (int i = 0; i < 2; i++) { int cid = tid + i * 256; xrow[i] = cid >> 3; xc[i] = cid & 7; }
#pragma unroll
  for (int i = 0; i < 4; i++) { int cid = tid + i * 256; wrow[i] = cid >> 3; wc[i] = cid & 7; }

  auto loadx = [&](int k0) {
#pragma unroll
    for (int i = 0; i < 2; i++) {
      const float* p = xb + xrow[i] * DD + k0 + xc[i] * 8;
      xr[i][0] = *(const float4*)p; xr[i][1] = *(const float4*)(p + 4);
    }
  };
  auto loadw = [&](int k0) {
#pragma unroll
    for (int i = 0; i < 4; i++) {
      const float* p = wg + (size_t)wrow[i] * DD + k0 + wc[i] * 8;
      wr[i][0] = *(const float4*)p; wr[i][1] = *(const float4*)(p + 4);
    }
  };
  auto store = [&](int buf) {
#pragma unroll
    for (int i = 0; i < 2; i++) {
      uint4 u;
      u.x = pk_bf16(xr[i][0].x, xr[i][0].y); u.y = pk_bf16(xr[i][0].z, xr[i][0].w);
      u.z = pk_bf16(xr[i][1].x, xr[i][1].y); u.w = pk_bf16(xr[i][1].z, xr[i][1].w);
      int p = xc[i] ^ (xrow[i] & 7);
      *(uint4*)&xa[buf][xrow[i]][p * 8] = u;
    }
#pragma unroll
    for (int i = 0; i < 4; i++) {
      uint4 u;
      u.x = pk_bf16(wr[i][0].x, wr[i][0].y); u.y = pk_bf16(wr[i][0].z, wr[i][0].w);
      u.z = pk_bf16(wr[i][1].x, wr[i][1].y); u.w = pk_bf16(wr[i][1].z, wr[i][1].w);
      int p = wc[i] ^ (wrow[i] & 7);
      *(uint4*)&wbuf[buf][wrow[i]][p * 8] = u;
    }
  };

  loadx(0); loadw(0); store(0);
  __syncthreads();

  f32x4 zero = {0.f, 0.f, 0.f, 0.f};
  f32x4 acc[2][4];
#pragma unroll
  for (int mt = 0; mt < 2; mt++)
#pragma unroll
    for (int nt = 0; nt < 4; nt++) acc[mt][nt] = zero;

  for (int s = 0; s < 8; s++) {
    const int nb = s & 1;
    if (s < 7) { loadx((s + 1) * 64); loadw((s + 1) * 64); }
#pragma unroll
    for (int ks = 0; ks < 2; ks++) {
      const int cc = ks * 4 + (lane >> 4);
      bf16x8 a[2], b[4];
#pragma unroll
      for (int mt = 0; mt < 2; mt++) {
        int r = wm * 32 + mt * 16 + (lane & 15);
        a[mt] = *(const bf16x8*)&xa[nb][r][(cc ^ (r & 7)) * 8];
      }
#pragma unroll
      for (int nt = 0; nt < 4; nt++) {
        int r = wn * 64 + nt * 16 + (lane & 15);
        b[nt] = *(const bf16x8*)&wbuf[nb][r][(cc ^ (r & 7)) * 8];
      }
#pragma unroll
      for (int mt = 0; mt < 2; mt++)
#pragma unroll
        for (int nt = 0; nt < 4; nt++)
          acc[mt][nt] = __builtin_amdgcn_mfma_f32_16x16x32_bf16(a[mt], b[nt], acc[mt][nt], 0, 0, 0);
    }
    __syncthreads();
    if (s < 7) store(nb ^ 1);
    __syncthreads();
  }

  float bias[4]; int jn[4];
#pragma unroll
  for (int nt = 0; nt < 4; nt++) {
    jn[nt] = j0 + wn * 64 + nt * 16 + (lane & 15);
    bias[nt] = bih[t * G4 + jn[nt]] + bhh[t * G4 + jn[nt]];
  }
#pragma unroll
  for (int mt = 0; mt < 2; mt++)
#pragma unroll
    for (int nt = 0; nt < 4; nt++)
#pragma unroll
      for (int e = 0; e < 4; e++) {
        int brow = wm * 32 + mt * 16 + (lane >> 4) * 4 + e;
        Gb[((size_t)t * BB + brow) * G4 + jn[nt]] = acc[mt][nt][e] + bias[nt];
      }
}

// ============================================================================
// Persistent LSTM stepper — round-10 protocol + zero-VGPR W-streamer wave.
// 256 blocks (bh = bid&1, ug = bid>>1 -> units ug*4..+3), 5 waves (320 thr):
//   waves 0-3: EXACT round-10 GEMM/epilogue/publish protocol, except W frags
//     come from LDS (ds_read fp32 + cvt_pk) -> their vmcnt holds ONLY poll
//     (and wave0's prefG) loads; no W-drain on the critical path.
//   wave 4: streams Whh(t+1) fp32 -> LDS double buffer via global_load_lds
//     (no data VGPRs, own vmcnt), source addresses PRE-SWIZZLED per-lane so
//     the linear LDS fill realizes the 16B-granule XOR swizzle pg = lg^(r&7).
// h in global as 16B TAGGED RECORDS [8B = 4 bf16][4B tag][pad], 2-slot
// ping-pong, sc0/sc1. Publish = data store; poll = data-carrying.
// ============================================================================
__global__ __launch_bounds__(320, 1) void lstm_persist(
    const float* __restrict__ whh, const float* __restrict__ Gb,
    const int* __restrict__ lengths, char* __restrict__ hb,
    float* __restrict__ hf) {
  __shared__ float wbufF[2][16 * 512];  // 64 KB fp32 W double buffer (swizzled)
  __shared__ float gm[2][16][36];

  const int tid = threadIdx.x, bid = blockIdx.x;
  const int bh = bid & 1, ug = bid >> 1;
  const int wv = tid >> 6, lane = tid & 63;
  const int l15 = lane & 15, klg = lane >> 4;

  if (wv < 4) {
    // ================= GEMM + epilogue waves (round-10 protocol) =============
    const int wm = wv & 1, kq = wv >> 1;

    float2 gpre[4];  // Gb prefetch (wave0: 2 units per lane)
    auto prefG = [&](int tt) {
      if (wv == 0) {
        const float* gbp =
            Gb + ((size_t)tt * BB + bh * 32 + (lane & 31)) * G4 + ug * 4 + ((lane >> 5) << 1);
#pragma unroll
        for (int q = 0; q < 4; q++) gpre[q] = *(const float2*)(gbp + q * 512);
      }
    };

    const size_t cbase =
        (size_t)bh * 65536 + ((size_t)(kq * 64 + klg * 2) * 32 + wm * 16 + l15) * 16;
    const size_t pbase = (size_t)bh * 65536 + ((size_t)ug * 32 + (lane & 31)) * 16;

    const int mylen = (wv == 0) ? lengths[bh * 32 + (lane & 31)] : -2;
    float cst[2] = {0.f, 0.f};

    prefG(0);

    for (int t = 0; t < TT; t++) {
      f32x4 acc = {0.f, 0.f, 0.f, 0.f};
      if (t > 0) {
        // ---- poll records(t): data-carrying, 1 LLC RT on success ----
        u32x4 r0[8], r1[8];
        const char* sbase = hb + (size_t)(t & 1) * 131072 + cbase;
        const unsigned tg = (unsigned)t;
        bool ok;
        do {
#pragma unroll
          for (int s = 0; s < 8; s++) {
            r0[s] = load_b128_cc(sbase + (size_t)s * 4096);
            r1[s] = load_b128_cc(sbase + (size_t)s * 4096 + 512);
          }
          asm volatile("s_waitcnt vmcnt(0)" ::: "memory");
          __builtin_amdgcn_sched_barrier(0);
          ok = true;
#pragma unroll
          for (int s = 0; s < 8; s++) ok = ok && (r0[s].z == tg) && (r1[s].z == tg);
          if (!__all(ok)) {
            __builtin_amdgcn_s_sleep(1);
            ok = false;
          } else {
            ok = true;
          }
        } while (!ok);

        // ---- W fragments from streamer-filled LDS (fp32 -> bf16 in-reg) ----
        const char* wrow = (const char*)&wbufF[t & 1][0] + l15 * 2048;
        bf16x8 wf[8];
#pragma unroll
        for (int s = 0; s < 8; s++) {
          int cc = kq * 32 + s * 4 + klg;
          int pg0 = (cc * 2) ^ (l15 & 7);
          int pg1 = (cc * 2 + 1) ^ (l15 & 7);
          f32x4 f0 = *(const f32x4*)(wrow + pg0 * 16);
          f32x4 f1 = *(const f32x4*)(wrow + pg1 * 16);
          uint4 u;
          u.x = pk_bf16(f0[0], f0[1]); u.y = pk_bf16(f0[2], f0[3]);
          u.z = pk_bf16(f1[0], f1[1]); u.w = pk_bf16(f1[2], f1[3]);
          wf[s] = __builtin_bit_cast(bf16x8, u);
        }
#pragma unroll
        for (int s = 0; s < 8; s++) {
          u32x4 fa;
          fa.x = r0[s].x; fa.y = r0[s].y; fa.z = r1[s].x; fa.w = r1[s].y;
          acc = __builtin_amdgcn_mfma_f32_16x16x32_bf16(__builtin_bit_cast(bf16x8, fa),
                                                        wf[s], acc, 0, 0, 0);
        }
      }
      *(f32x4*)&gm[kq][l15][wm * 16 + klg * 4] = acc;

      __syncthreads();

      float2 gcur[4];
      if (wv == 0) {
#pragma unroll
        for (int q = 0; q < 4; q++) gcur[q] = gpre[q];
      }
      if (t + 1 < TT) prefG(t + 1);

      if (wv == 0) {
        const int b = lane & 31, hi = lane >> 5;
        float hv[2];
#pragma unroll
        for (int uu = 0; uu < 2; uu++) {
          const int lu = hi * 2 + uu;
          float vi = (uu ? gcur[0].y : gcur[0].x) + gm[0][0 + lu][b] + gm[1][0 + lu][b];
          float vf = (uu ? gcur[1].y : gcur[1].x) + gm[0][4 + lu][b] + gm[1][4 + lu][b];
          float vg = (uu ? gcur[2].y : gcur[2].x) + gm[0][8 + lu][b] + gm[1][8 + lu][b];
          float vo = (uu ? gcur[3].y : gcur[3].x) + gm[0][12 + lu][b] + gm[1][12 + lu][b];
          float cn = fsigm(vf) * cst[uu] + fsigm(vi) * ftanh(vg);
          cst[uu] = cn;
          hv[uu] = fsigm(vo) * ftanh(cn);
        }
        // publish FIRST (cross-block critical path), hf store after
        unsigned hw = pk_bf16(hv[0], hv[1]);
        unsigned other = __shfl_xor(hw, 32);
        if (hi == 0 && t + 1 < TT) {
          u32x4 rec;
          rec.x = hw; rec.y = other; rec.z = (unsigned)(t + 1); rec.w = 0u;
          store_b128_cc(hb + (size_t)((t + 1) & 1) * 131072 + pbase, rec);
        }
        if (mylen - 1 == t) {
          float2 o2; o2.x = hv[0]; o2.y = hv[1];
          *(float2*)&hf[(size_t)(bh * 32 + b) * HH + ug * 4 + hi * 2] = o2;
        }
      }
    }
  } else {
    // ================= W-streamer wave (wv == 4): HBM -> LDS DMA =============
    // Fills slot (t+1)&1 during step t; 32 x global_load_lds (1 KB each).
    // Instruction i: row r = i>>1, phys granule pg = (i&1)*64 + lane,
    // logical granule lg = pg ^ (r&7); global row j = (r>>2)*512 + ug*4 + (r&3).
    for (int t = 0; t < TT; t++) {
      if (t + 1 < TT) {
        const char* wt = (const char*)(whh + (size_t)(t + 1) * (G4 * HH));
        char* ldsb = (char*)&wbufF[(t + 1) & 1][0];
#pragma unroll
        for (int i = 0; i < 32; i++) {
          const int r = i >> 1;
          const int j = (r >> 2) * 512 + ug * 4 + (r & 3);
          const int lg = (((i & 1) << 6) | lane) ^ (r & 7);
          gload_lds16(wt + (size_t)j * 2048 + (size_t)lg * 16, ldsb + i * 1024);
        }
        asm volatile("s_waitcnt vmcnt(0)" ::: "memory");
      }
      __syncthreads();
    }
  }
}

// ============================================================================
// Final: logits = hf @ w_ho^T + b_ho, then log_softmax
// ============================================================================
__global__ __launch_bounds__(128) void finalK(const float* __restrict__ hf,
                                              const float* __restrict__ who,
                                              const float* __restrict__ bho,
                                              float* __restrict__ out) {
  int b = blockIdx.x, o = threadIdx.x;
  const float* h = hf + b * HH;
  const float* w = who + o * HH;
  float s = bho[o];
#pragma unroll 4
  for (int k = 0; k < HH; k += 4) {
    float4 hv = *(const float4*)(h + k);
    float4 wv = *(const float4*)(w + k);
    s += hv.x * wv.x + hv.y * wv.y + hv.z * wv.z + hv.w * wv.w;
  }
  __shared__ float red[2];
  __shared__ float red2[2];
  float m = s;
#pragma unroll
  for (int msk = 32; msk; msk >>= 1) m = fmaxf(m, __shfl_xor(m, msk));
  int wave = o >> 6;
  if ((o & 63) == 0) red[wave] = m;
  __syncthreads();
  m = fmaxf(red[0], red[1]);
  float e = expf(s - m);
#pragma unroll
  for (int msk = 32; msk; msk >>= 1) e += __shfl_xor(e, msk);
  if ((o & 63) == 0) red2[wave] = e;
  __syncthreads();
  float sum = red2[0] + red2[1];
  out[b * OO + o] = (s - m) - logf(sum);
}

extern "C" void kernel_launch(void* const* d_in, const int* in_sizes, int n_in,
                              void* d_out, int out_size, void* d_ws, size_t ws_size,
                              hipStream_t stream) {
  const float* x = (const float*)d_in[0];
  const float* wih = (const float*)d_in[1];
  const float* whh = (const float*)d_in[2];
  const float* bih = (const float*)d_in[3];
  const float* bhh = (const float*)d_in[4];
  const float* who = (const float*)d_in[5];
  const float* bho = (const float*)d_in[6];
  const int* lengths = (const int*)d_in[7];
  float* out = (float*)d_out;

  char* ws = (char*)d_ws;
  float* Gb = (float*)ws;                        // 33,554,432 B
  char* hb = ws + 33554432;                      // 262,144 B (2 slots x 2 halves x 4096 records)
  float* hf = (float*)(ws + 33554432 + 262144);  // 131,072 B

  (void)hipMemsetAsync(hb, 0, 262144, stream);  // clear tags (graph-replay safety)

  phaseA_mfma<<<dim3(16, 64), 256, 0, stream>>>(x, wih, bih, bhh, Gb);
  lstm_persist<<<256, 320, 0, stream>>>(whh, Gb, lengths, hb, hf);
  finalK<<<BB, 128, 0, stream>>>(hf, who, bho, out);
}

// Round 14
// 374.428 us; speedup vs baseline: 2.5366x; 1.0345x over previous
//
#include <hip/hip_runtime.h>
#include <math.h>

#define TT 64
#define BB 64
#define DD 512
#define HH 512
#define G4 2048
#define OO 128

typedef unsigned short us16;
typedef __attribute__((ext_vector_type(8))) short bf16x8;
typedef __attribute__((ext_vector_type(4))) float f32x4;
typedef __attribute__((ext_vector_type(4))) unsigned u32x4;

__device__ __forceinline__ unsigned pk_bf16(float lo, float hi) {
  unsigned r;
  asm volatile("v_cvt_pk_bf16_f32 %0, %1, %2" : "=v"(r) : "v"(lo), "v"(hi));
  return r;
}

// fast gate math (bf16 tolerance is ample)
__device__ __forceinline__ float fsigm(float v) { return 1.f / (1.f + __expf(-v)); }
__device__ __forceinline__ float ftanh(float v) { return 1.f - 2.f / (__expf(2.f * v) + 1.f); }

// coherent (LLC-direct) accesses for cross-block data
__device__ __forceinline__ u32x4 load_b128_cc(const void* p) {
  u32x4 r;
  asm volatile("global_load_dwordx4 %0, %1, off sc0 sc1" : "=v"(r) : "v"(p));
  return r;
}
__device__ __forceinline__ void store_b128_cc(void* p, u32x4 v) {
  asm volatile("global_store_dwordx4 %0, %1, off sc0 sc1" ::"v"(p), "v"(v) : "memory");
}

// ============================================================================
// Phase A: G[t,b,j] = x_t @ Wih_t^T + b_ih + b_hh   via bf16 MFMA  (unchanged)
// ============================================================================
__global__ __launch_bounds__(256) void phaseA_mfma(
    const float* __restrict__ x, const float* __restrict__ wih,
    const float* __restrict__ bih, const float* __restrict__ bhh,
    float* __restrict__ Gb) {
  __shared__ us16 xa[2][64][64];
  __shared__ us16 wbuf[2][128][64];
  const int tid = threadIdx.x;
  const int t = blockIdx.y;
  const int j0 = blockIdx.x * 128;
  const int wv = tid >> 6, lane = tid & 63;
  const int wm = wv & 1, wn = wv >> 1;
  const float* xb = x + (size_t)t * (BB * DD);
  const float* wg = wih + (size_t)t * (G4 * DD) + (size_t)j0 * DD;

  float4 xr[2][2], wr[4][2];
  int xrow[2], xc[2], wrow[4], wc[4];
#pragma unroll
  for (int i = 0; i < 2; i++) { int cid = tid + i * 256; xrow[i] = cid >> 3; xc[i] = cid & 7; }
#pragma unroll
  for (int i = 0; i < 4; i++) { int cid = tid + i * 256; wrow[i] = cid >> 3; wc[i] = cid & 7; }

  auto loadx = [&](int k0) {
#pragma unroll
    for (int i = 0; i < 2; i++) {
      const float* p = xb + xrow[i] * DD + k0 + xc[i] * 8;
      xr[i][0] = *(const float4*)p; xr[i][1] = *(const float4*)(p + 4);
    }
  };
  auto loadw = [&](int k0) {
#pragma unroll
    for (int i = 0; i < 4; i++) {
      const float* p = wg + (size_t)wrow[i] * DD + k0 + wc[i] * 8;
      wr[i][0] = *(const float4*)p; wr[i][1] = *(const float4*)(p + 4);
    }
  };
  auto store = [&](int buf) {
#pragma unroll
    for (int i = 0; i < 2; i++) {
      uint4 u;
      u.x = pk_bf16(xr[i][0].x, xr[i][0].y); u.y = pk_bf16(xr[i][0].z, xr[i][0].w);
      u.z = pk_bf16(xr[i][1].x, xr[i][1].y); u.w = pk_bf16(xr[i][1].z, xr[i][1].w);
      int p = xc[i] ^ (xrow[i] & 7);
      *(uint4*)&xa[buf][xrow[i]][p * 8] = u;
    }
#pragma unroll
    for (int i = 0; i < 4; i++) {
      uint4 u;
      u.x = pk_bf16(wr[i][0].x, wr[i][0].y); u.y = pk_bf16(wr[i][0].z, wr[i][0].w);
      u.z = pk_bf16(wr[i][1].x, wr[i][1].y); u.w = pk_bf16(wr[i][1].z, wr[i][1].w);
      int p = wc[i] ^ (wrow[i] & 7);
      *(uint4*)&wbuf[buf][wrow[i]][p * 8] = u;
    }
  };

  loadx(0); loadw(0); store(0);
  __syncthreads();

  f32x4 zero = {0.f, 0.f, 0.f, 0.f};
  f32x4 acc[2][4];
#pragma unroll
  for (int mt = 0; mt < 2; mt++)
#pragma unroll
    for (int nt = 0; nt < 4; nt++) acc[mt][nt] = zero;

  for (int s = 0; s < 8; s++) {
    const int nb = s & 1;
    if (s < 7) { loadx((s + 1) * 64); loadw((s + 1) * 64); }
#pragma unroll
    for (int ks = 0; ks < 2; ks++) {
      const int cc = ks * 4 + (lane >> 4);
      bf16x8 a[2], b[4];
#pragma unroll
      for (int mt = 0; mt < 2; mt++) {
        int r = wm * 32 + mt * 16 + (lane & 15);
        a[mt] = *(const bf16x8*)&xa[nb][r][(cc ^ (r & 7)) * 8];
      }
#pragma unroll
      for (int nt = 0; nt < 4; nt++) {
        int r = wn * 64 + nt * 16 + (lane & 15);
        b[nt] = *(const bf16x8*)&wbuf[nb][r][(cc ^ (r & 7)) * 8];
      }
#pragma unroll
      for (int mt = 0; mt < 2; mt++)
#pragma unroll
        for (int nt = 0; nt < 4; nt++)
          acc[mt][nt] = __builtin_amdgcn_mfma_f32_16x16x32_bf16(a[mt], b[nt], acc[mt][nt], 0, 0, 0);
    }
    __syncthreads();
    if (s < 7) store(nb ^ 1);
    __syncthreads();
  }

  float bias[4]; int jn[4];
#pragma unroll
  for (int nt = 0; nt < 4; nt++) {
    jn[nt] = j0 + wn * 64 + nt * 16 + (lane & 15);
    bias[nt] = bih[t * G4 + jn[nt]] + bhh[t * G4 + jn[nt]];
  }
#pragma unroll
  for (int mt = 0; mt < 2; mt++)
#pragma unroll
    for (int nt = 0; nt < 4; nt++)
#pragma unroll
      for (int e = 0; e < 4; e++) {
        int brow = wm * 32 + mt * 16 + (lane >> 4) * 4 + e;
        Gb[((size_t)t * BB + brow) * G4 + jn[nt]] = acc[mt][nt][e] + bias[nt];
      }
}

// ============================================================================
// Persistent LSTM stepper — r10 protocol + bf16-LDS W-streamer wave.
// 256 blocks (bh = bid&1, ug = bid>>1 -> units ug*4..+3), 5 waves (320 thr):
//   waves 0-3: r10 GEMM/epilogue/publish EXACTLY, but W fragments come from a
//     bf16 LDS ring via 8 ds_read_b128 issued BEFORE the poll (lgkm != vmcnt
//     -> LDS latency hides under the poll; ZERO W work after the poll).
//   wave 4: streams Whh into a 3-slot LDS ring with lookahead 2 (fill slot
//     (t+2)%3 during step t -> 2-step flight). Depth-2 quarter pipeline keeps
//     its data registers at 64 (r11's spill killer avoided). It converts to
//     bf16 itself (r12's post-poll fp32 ds_read+cvt killer avoided).
// Slot safety with ONE barrier/step + one prologue barrier: writer touches
// slot (t+2)%3 in window (bar t-1, bar t]; readers touch slot t%3 in the same
// window -> disjoint; reader of slot X at iter t+2 is after bar t+1 > writer.
// h records: 16B tagged [8B = 4 bf16][4B tag][pad], 2-slot ping-pong, sc0/sc1.
// ============================================================================
__global__ __launch_bounds__(320, 1) void lstm_persist(
    const float* __restrict__ whh, const float* __restrict__ Gb,
    const int* __restrict__ lengths, char* __restrict__ hb,
    float* __restrict__ hf) {
  __shared__ us16 wbuf3[3][16][512];  // 48 KB bf16 W ring (granule-XOR swizzled)
  __shared__ float gm[2][16][36];

  const int tid = threadIdx.x, bid = blockIdx.x;
  const int bh = bid & 1, ug = bid >> 1;
  const int wv = tid >> 6, lane = tid & 63;
  const int l15 = lane & 15, klg = lane >> 4;

  if (wv == 4) {
    // =================== W-streamer wave ===================
    const int r_ = lane >> 4, gq = lane & 15;
    auto fillW = [&](int tt, int sl) {
      const float* wt = whh + (size_t)tt * (G4 * HH);
      float4 ra[8], rb[8];
      auto issueQ = [&](int q, float4(&rr)[8]) {
        int r = q * 4 + r_;
        const float* src = wt + (size_t)((r >> 2) * 512 + ug * 4 + (r & 3)) * HH;
#pragma unroll
        for (int jj = 0; jj < 4; jj++) {
          int g = gq + 16 * jj;
          rr[2 * jj] = *(const float4*)(src + g * 8);
          rr[2 * jj + 1] = *(const float4*)(src + g * 8 + 4);
        }
      };
      auto writeQ = [&](int q, float4(&rr)[8]) {
        int r = q * 4 + r_;
#pragma unroll
        for (int jj = 0; jj < 4; jj++) {
          int g = gq + 16 * jj;
          u32x4 w;
          w.x = pk_bf16(rr[2 * jj].x, rr[2 * jj].y);
          w.y = pk_bf16(rr[2 * jj].z, rr[2 * jj].w);
          w.z = pk_bf16(rr[2 * jj + 1].x, rr[2 * jj + 1].y);
          w.w = pk_bf16(rr[2 * jj + 1].z, rr[2 * jj + 1].w);
          *(u32x4*)&wbuf3[sl][r][(g ^ (r & 7)) * 8] = w;
        }
      };
      issueQ(0, ra); issueQ(1, rb);
      writeQ(0, ra); issueQ(2, ra);
      writeQ(1, rb); issueQ(3, rb);
      writeQ(2, ra);
      writeQ(3, rb);
    };
    fillW(0, 0);
    fillW(1, 1);
    __syncthreads();  // prologue barrier (all 5 waves)
    int slW = 2;
    for (int t = 0; t < TT; t++) {
      if (t + 2 < TT) fillW(t + 2, slW);
      slW = (slW + 1 == 3) ? 0 : slW + 1;
      __syncthreads();  // mid-loop barrier (shared with GEMM waves)
    }
    return;
  }

  // =================== GEMM + epilogue waves (r10 protocol) ===================
  const int wm = wv & 1, kq = wv >> 1;

  float2 gpre[4];  // Gb prefetch (wave0: 2 units per lane)
  auto prefG = [&](int tt) {
    if (wv == 0) {
      const float* gbp =
          Gb + ((size_t)tt * BB + bh * 32 + (lane & 31)) * G4 + ug * 4 + ((lane >> 5) << 1);
#pragma unroll
      for (int q = 0; q < 4; q++) gpre[q] = *(const float2*)(gbp + q * 512);
    }
  };

  // consumer record base: record (u4, m) at half_base + (u4*32 + m)*16
  const size_t cbase =
      (size_t)bh * 65536 + ((size_t)(kq * 64 + klg * 2) * 32 + wm * 16 + l15) * 16;
  // producer (wave0, lanes 0..31): u4 = ug, m = lane
  const size_t pbase = (size_t)bh * 65536 + ((size_t)ug * 32 + (lane & 31)) * 16;

  const int mylen = (wv == 0) ? lengths[bh * 32 + (lane & 31)] : -2;
  float cst[2] = {0.f, 0.f};

  prefG(0);
  __syncthreads();  // prologue barrier: W slots 0,1 visible
  int slR = 0;

  for (int t = 0; t < TT; t++) {
    // ---- W fragments from LDS ring: issued BEFORE the poll, consumed after ----
    bf16x8 wf[8];
#pragma unroll
    for (int s = 0; s < 8; s++) {
      int cc = kq * 32 + s * 4 + klg;
      wf[s] = *(const bf16x8*)&wbuf3[slR][l15][(cc ^ (l15 & 7)) * 8];
    }
    slR = (slR + 1 == 3) ? 0 : slR + 1;

    // ---- poll records(t): data-carrying, 1 LLC RT on success ----
    u32x4 r0[8], r1[8];
    if (t == 0) {
      u32x4 z = {0u, 0u, 0u, 0u};
#pragma unroll
      for (int s = 0; s < 8; s++) { r0[s] = z; r1[s] = z; }
    } else {
      const char* sbase = hb + (size_t)(t & 1) * 131072 + cbase;
      const unsigned tg = (unsigned)t;
      bool ok;
      do {
#pragma unroll
        for (int s = 0; s < 8; s++) {
          r0[s] = load_b128_cc(sbase + (size_t)s * 4096);
          r1[s] = load_b128_cc(sbase + (size_t)s * 4096 + 512);
        }
        asm volatile("s_waitcnt vmcnt(0)" ::: "memory");
        __builtin_amdgcn_sched_barrier(0);
        ok = true;
#pragma unroll
        for (int s = 0; s < 8; s++) ok = ok && (r0[s].z == tg) && (r1[s].z == tg);
        if (!__all(ok)) {
          __builtin_amdgcn_s_sleep(1);  // backoff: don't hammer the LLC
          ok = false;
        } else {
          ok = true;
        }
      } while (!ok);
    }

    f32x4 acc = {0.f, 0.f, 0.f, 0.f};
#pragma unroll
    for (int s = 0; s < 8; s++) {
      u32x4 fa;
      fa.x = r0[s].x; fa.y = r0[s].y; fa.z = r1[s].x; fa.w = r1[s].y;
      acc = __builtin_amdgcn_mfma_f32_16x16x32_bf16(__builtin_bit_cast(bf16x8, fa),
                                                    wf[s], acc, 0, 0, 0);
    }
    *(f32x4*)&gm[kq][l15][wm * 16 + klg * 4] = acc;

    __syncthreads();  // mid-loop barrier (shared with streamer)

    float2 gcur[4];
    if (wv == 0) {
#pragma unroll
      for (int q = 0; q < 4; q++) gcur[q] = gpre[q];
    }
    if (t + 1 < TT) prefG(t + 1);  // streams during epilogue + next poll

    if (wv == 0) {
      const int b = lane & 31, hi = lane >> 5;
      float hv[2];
#pragma unroll
      for (int uu = 0; uu < 2; uu++) {
        const int lu = hi * 2 + uu;
        float vi = (uu ? gcur[0].y : gcur[0].x) + gm[0][0 + lu][b] + gm[1][0 + lu][b];
        float vf = (uu ? gcur[1].y : gcur[1].x) + gm[0][4 + lu][b] + gm[1][4 + lu][b];
        float vg = (uu ? gcur[2].y : gcur[2].x) + gm[0][8 + lu][b] + gm[1][8 + lu][b];
        float vo = (uu ? gcur[3].y : gcur[3].x) + gm[0][12 + lu][b] + gm[1][12 + lu][b];
        float cn = fsigm(vf) * cst[uu] + fsigm(vi) * ftanh(vg);
        cst[uu] = cn;
        hv[uu] = fsigm(vo) * ftanh(cn);
      }
      // publish FIRST (cross-block critical path), hf store after
      unsigned hw = pk_bf16(hv[0], hv[1]);
      unsigned other = __shfl_xor(hw, 32);
      if (hi == 0 && t + 1 < TT) {
        u32x4 rec;
        rec.x = hw; rec.y = other; rec.z = (unsigned)(t + 1); rec.w = 0u;
        store_b128_cc(hb + (size_t)((t + 1) & 1) * 131072 + pbase, rec);
      }
      if (mylen - 1 == t) {
        float2 o2; o2.x = hv[0]; o2.y = hv[1];
        *(float2*)&hf[(size_t)(bh * 32 + b) * HH + ug * 4 + hi * 2] = o2;
      }
    }
  }
}

// ============================================================================
// Final: logits = hf @ w_ho^T + b_ho, then log_softmax
// ============================================================================
__global__ __launch_bounds__(128) void finalK(const float* __restrict__ hf,
                                              const float* __restrict__ who,
                                              const float* __restrict__ bho,
                                              float* __restrict__ out) {
  int b = blockIdx.x, o = threadIdx.x;
  const float* h = hf + b * HH;
  const float* w = who + o * HH;
  float s = bho[o];
#pragma unroll 4
  for (int k = 0; k < HH; k += 4) {
    float4 hv = *(const float4*)(h + k);
    float4 wv = *(const float4*)(w + k);
    s += hv.x * wv.x + hv.y * wv.y + hv.z * wv.z + hv.w * wv.w;
  }
  __shared__ float red[2];
  __shared__ float red2[2];
  float m = s;
#pragma unroll
  for (int msk = 32; msk; msk >>= 1) m = fmaxf(m, __shfl_xor(m, msk));
  int wave = o >> 6;
  if ((o & 63) == 0) red[wave] = m;
  __syncthreads();
  m = fmaxf(red[0], red[1]);
  float e = expf(s - m);
#pragma unroll
  for (int msk = 32; msk; msk >>= 1) e += __shfl_xor(e, msk);
  if ((o & 63) == 0) red2[wave] = e;
  __syncthreads();
  float sum = red2[0] + red2[1];
  out[b * OO + o] = (s - m) - logf(sum);
}

extern "C" void kernel_launch(void* const* d_in, const int* in_sizes, int n_in,
                              void* d_out, int out_size, void* d_ws, size_t ws_size,
                              hipStream_t stream) {
  const float* x = (const float*)d_in[0];
  const float* wih = (const float*)d_in[1];
  const float* whh = (const float*)d_in[2];
  const float* bih = (const float*)d_in[3];
  const float* bhh = (const float*)d_in[4];
  const float* who = (const float*)d_in[5];
  const float* bho = (const float*)d_in[6];
  const int* lengths = (const int*)d_in[7];
  float* out = (float*)d_out;

  char* ws = (char*)d_ws;
  float* Gb = (float*)ws;                        // 33,554,432 B
  char* hb = ws + 33554432;                      // 262,144 B (2 slots x 2 halves x 4096 records)
  float* hf = (float*)(ws + 33554432 + 262144);  // 131,072 B

  (void)hipMemsetAsync(hb, 0, 262144, stream);  // clear tags (graph-replay safety)

  phaseA_mfma<<<dim3(16, 64), 256, 0, stream>>>(x, wih, bih, bhh, Gb);
  lstm_persist<<<256, 320, 0, stream>>>(whh, Gb, lengths, hb, hf);
  finalK<<<BB, 128, 0, stream>>>(hf, who, bho, out);
}